// Round 2
// baseline (54.836 us; speedup 1.0000x reference)
//
#include <hip/hip_runtime.h>
#include <hip/hip_bf16.h>

// Analytic reduction of the circuit:
//   out[b,w] = prod_{v=0..w} cos(inputs[b,v])
// (rz_params cancels in |amplitude|^2; the CNOT chain is a classical basis
// permutation making bit w the prefix-XOR, whose expectation factorizes into
// a product of cos(theta_v) over v <= w.)
//
// B=8192, n=10. Two rows per thread: 2 rows = 20 floats = exactly five
// 16B-aligned float4s (row pair starts at 80*t bytes). 5 vec loads + 5 vec
// stores replace 20 scalar loads + 20 scalar stores.

#ifndef NWIRES
#define NWIRES 10
#endif

__global__ __launch_bounds__(256) void quantum_cumcos2_kernel(
    const float4* __restrict__ in4,   // (B*10/4) float4
    float4* __restrict__ out4,        // same
    int Bpairs)                        // B/2
{
    int t = blockIdx.x * blockDim.x + threadIdx.x;
    if (t >= Bpairs) return;

    float4 v[5];
    const float4* p = in4 + (size_t)t * 5;
#pragma unroll
    for (int i = 0; i < 5; ++i) v[i] = p[i];

    float* f = (float*)v;  // rows 2t (f[0..9]) and 2t+1 (f[10..19])

    float acc = 1.0f;
#pragma unroll
    for (int w = 0; w < NWIRES; ++w) { acc *= __cosf(f[w]); f[w] = acc; }

    acc = 1.0f;
#pragma unroll
    for (int w = NWIRES; w < 2 * NWIRES; ++w) { acc *= __cosf(f[w]); f[w] = acc; }

    float4* q = out4 + (size_t)t * 5;
#pragma unroll
    for (int i = 0; i < 5; ++i) q[i] = v[i];
}

extern "C" void kernel_launch(void* const* d_in, const int* in_sizes, int n_in,
                              void* d_out, int out_size, void* d_ws, size_t ws_size,
                              hipStream_t stream) {
    const float4* in4 = (const float4*)d_in[0];   // (B, n) float32, n=10
    float4* out4 = (float4*)d_out;

    const int B = in_sizes[0] / NWIRES;   // 8192
    const int Bpairs = B / 2;             // 4096

    const int block = 256;
    const int grid = (Bpairs + block - 1) / block;  // 16 blocks
    quantum_cumcos2_kernel<<<grid, block, 0, stream>>>(in4, out4, Bpairs);
}